// Round 11
// baseline (137.396 us; speedup 1.0000x reference)
//
#include <hip/hip_runtime.h>
#include <hip/hip_bf16.h>

// BlurredNoise via MFMA implicit GEMM, round 19 = A-from-global (LDS staging
// deleted). R18 budget per CU (136k cyc): MFMA 34k, A ds_read_b128 31k,
// stage-writes 6.5k, bank conflicts 13k (3.3M persists despite CSTRIDE fix),
// VALU 11k, B-VMEM 33k -> near-serial sum. Biggest removable block: the
// whole LDS x-staging (~50k), which exists only to realign bf16 A-frags.
// Key: g(s,row,hi,m) = t0+32m+row+8hi+4984-16s has g mod 4 = row mod 4,
// invariant across steps/m -> FOUR pre-shifted bf16 x copies in GLOBAL
// memory (built by build_pre) make every A-frag two 8B-aligned dwordx2
// loads at compile-time immediate offsets off one per-lane base pointer
// (-32B/step, -32*UB/iter). x window is L1/L2-hot. LDS keeps only the 16KB
// cross-wave reduction. B-path, k-split, reduction, epilogue = R18.
// out[bc][F][t] = scale[F] * sum_j x[bc][t+j] * k[F][j]

#define KS      5000
#define IN_SEQ  9095
#define T_OUT   4096
#define NBC     16
#define NF      128
#define SWZSTEP 352               // B rows per tile (s>=313 all-zero via clamp)
#define FRONT   192               // x front zero pad (elements)
#define XPS2    9344              // bf16 copy row stride (elements)
#define CS      (NBC*XPS2)        // bf16 copy stride (elements) = 149,504
#define SWZ_BYTES (4*SWZSTEP*1024)    // 1,441,792

typedef __attribute__((ext_vector_type(8)))  short v8s;
typedef __attribute__((ext_vector_type(4)))  float v4f;
typedef __attribute__((ext_vector_type(16))) float v16f;

__device__ __forceinline__ unsigned short f2b(float v) {
  union { __hip_bfloat16 h; unsigned short u; } cv;
  cv.h = __float2bfloat16(v);   // RNE
  return cv.u;
}

// ---- fused pre-kernel: (a) filters -> 32x32x16 B-frags; (b) 4 shifted bf16
// x copies: xb16[p][bc][i] = x_bc[i - FRONT + p], zeros outside ----
__global__ void build_pre(const float* __restrict__ filt,
                          const float* __restrict__ noise,
                          unsigned short* __restrict__ swz,
                          unsigned short* __restrict__ xb16) {
  const int b = blockIdx.x;
  if (b < 352) {                       // swz job: 4 tiles x 352 rows, 64 lanes/frag
    const int i = b * 256 + threadIdx.x;
    if (i >= 4 * SWZSTEP * 64) return;
    const int lane = i & 63;
    const int frag = i >> 6;
    const int ft = frag / SWZSTEP;
    const int s  = frag - ft * SWZSTEP;
    const int col = lane & 31;          // filter within tile
    const int hi  = lane >> 5;          // k-group (8 taps)
    const int jg0 = KS - 16 * (s + 1) + 8 * hi;
    const float* row = filt + (size_t)(ft * 32 + col) * KS;
    unsigned short o[8];
    #pragma unroll
    for (int j = 0; j < 8; ++j) {
      int jg = jg0 + j;
      int jc = jg < 0 ? 0 : jg;          // clamp ADDRESS, select VALUE
      float v = (jg >= 0 && jg < KS) ? row[jc] : 0.0f;
      o[j] = f2b(v);
    }
    *(uint4*)(swz + (((size_t)(ft * SWZSTEP + s)) << 9) + (lane << 3)) = *(uint4*)o;
  } else {                             // xb16 job: 4 copies x 16 rows x XPS2
    const int i = (b - 352) * 256 + threadIdx.x;
    if (i >= 4 * CS) return;
    const int p   = i / CS;
    const int rem = i - p * CS;
    const int r   = rem / XPS2;
    const int col = rem - r * XPS2;
    const int lg  = col - FRONT + p;
    const float v = (lg >= 0 && lg < IN_SEQ) ? noise[r * IN_SEQ + lg] : 0.0f;
    xb16[i] = f2b(v);
  }
}

// ---- one rolled region of the k-loop ----
// W: live 32-F tiles (tiles 4-W..3); UB: steps/window (UB%D==0); D: B-prefetch
// depth; sb0/iters RUNTIME. Per step: A ring prefetch dist 3 (2 m-streams,
// 2x dwordx2 each from the shifted-copy image, imm offsets), 2W MFMA, W
// B-refill dwordx4. All register indices compile-time (rule 20). No LDS.
template<int W, int UB, int D>
__device__ __forceinline__ void run_roll(
    const char* __restrict__ swzg, const char* __restrict__ abase,
    int lane, int sb0, int iters, v16f (&acc)[2][4])
{
  v8s breg[D][W];
  v8s areg[4][2];                      // [ring slot][m-stream]

  const char* sp[W];
  #pragma unroll
  for (int w = 0; w < W; ++w)
    sp[w] = swzg + (((size_t)((4 - W + w) * SWZSTEP + sb0)) << 10) + 16 * lane;

  const char* ap = abase - 32 * sb0;   // A byte ptr at region step 0

  // prologue: B depth D; A ring slots 0..2 = steps 0..2
  #pragma unroll
  for (int d = 0; d < D; ++d)
    #pragma unroll
    for (int w = 0; w < W; ++w)
      breg[d][w] = *(const v8s*)(sp[w] + (d << 10));
  #pragma unroll
  for (int j = 0; j < 3; ++j)
    #pragma unroll
    for (int m = 0; m < 2; ++m) {
      *(uint2*)&areg[j][m]       = *(const uint2*)(ap - 32 * j + 64 * m);
      *((uint2*)&areg[j][m] + 1) = *(const uint2*)(ap - 32 * j + 64 * m + 8);
    }

  #pragma unroll 1
  for (int g = 0; g < iters; ++g) {
    #pragma unroll
    for (int ii = 0; ii < UB; ++ii) {
      // A prefetch for step ii+3 (imm offsets; crosses windows linearly;
      // region-tail dead reads stay inside the padded image)
      #pragma unroll
      for (int m = 0; m < 2; ++m) {
        *(uint2*)&areg[(ii + 3) & 3][m] =
            *(const uint2*)(ap - 32 * (ii + 3) + 64 * m);
        *((uint2*)&areg[(ii + 3) & 3][m] + 1) =
            *(const uint2*)(ap - 32 * (ii + 3) + 64 * m + 8);
      }
      // MFMA: one A fragment per m-stream x W live B tiles (B shared)
      #pragma unroll
      for (int w = 0; w < W; ++w)
        #pragma unroll
        for (int m = 0; m < 2; ++m)
          acc[m][4 - W + w] = __builtin_amdgcn_mfma_f32_32x32x16_bf16(
              areg[ii & 3][m], breg[ii % D][w], acc[m][4 - W + w], 0, 0, 0);
      // B refill: slot ii%D <- step ii+D (tail over-reads: rows < SWZSTEP, dead)
      #pragma unroll
      for (int w = 0; w < W; ++w)
        breg[ii % D][w] = *(const v8s*)(sp[w] + ((ii + D) << 10));
    }
    #pragma unroll
    for (int w = 0; w < W; ++w) sp[w] += (UB << 10);
    ap -= 32 * UB;
  }
}

// ---- main kernel: 1024 blocks x 128 threads (2 waves k-split one 64t tile) ----
__global__ __launch_bounds__(128, 2) void blur_mfma(
    const unsigned short* __restrict__ xb16,
    const unsigned short* __restrict__ swz,
    const float* __restrict__ scale,
    float* __restrict__ out)
{
  __shared__ __align__(16) char xb[16384];   // reduction buffer only
  const int tid  = threadIdx.x;
  const int lane = tid & 63;
  const int wid  = tid >> 6;
  const int b  = blockIdx.x;
  const int bc = b >> 6;                 // 16 bc x 64 t-chunks
  const int t0 = (b & 63) << 6;          // 64 output t per block (2 m-tiles)
  const int row = lane & 31, hi = lane >> 5;
  const char* swzg = (const char*)swz;
  // A base (byte ptr, step s=0, m=0): copy p = row&3, element index
  // e = g - p with g = t0 + row + 8*hi + (KS-16); i = e + FRONT.
  const int p = row & 3;
  const char* abase = (const char*)xb16 +
      2 * ((size_t)p * CS + (size_t)bc * XPS2 +
           (FRONT + (row - p) + 8 * hi + t0 + KS - 16));

  v16f acc[2][4];
  #pragma unroll
  for (int m = 0; m < 2; ++m)
    #pragma unroll
    for (int n = 0; n < 4; ++n)
      #pragma unroll
      for (int j = 0; j < 16; ++j) acc[m][n][j] = 0.0f;

  // regions (live: W4 s<20, W3 <49, W2 <124, W1 <313; extras hit zero B rows)
  // wave0: W4 0..23 + W3 24..55 + W2 56..115   (116 steps, 312 tile-steps)
  // wave1: W2 116..127 + W1 128..319           (204 steps, 216 tile-steps)
  if (wid == 0) {
    run_roll<4, 24,  3>(swzg, abase, lane,   0, 1, acc);
    run_roll<3, 16,  4>(swzg, abase, lane,  24, 2, acc);
    run_roll<2, 12,  6>(swzg, abase, lane,  56, 5, acc);
  } else {
    run_roll<2, 12,  6>(swzg, abase, lane, 116, 1, acc);
    run_roll<1, 24, 12>(swzg, abase, lane, 128, 8, acc);
  }

  // cross-wave reduction: 2 rounds of 16KB LDS (conflict-free 16B/lane).
  __syncthreads();
  #pragma unroll
  for (int mm = 0; mm < 2; ++mm) {
    if (wid == 1) {
      #pragma unroll
      for (int n = 0; n < 4; ++n)
        #pragma unroll
        for (int r2 = 0; r2 < 4; ++r2) {
          v4f v = {acc[mm][n][4 * r2],     acc[mm][n][4 * r2 + 1],
                   acc[mm][n][4 * r2 + 2], acc[mm][n][4 * r2 + 3]};
          *(v4f*)(xb + ((n * 4 + r2) << 10) + 16 * lane) = v;
        }
    }
    __syncthreads();
    if (wid == 0) {
      #pragma unroll
      for (int n = 0; n < 4; ++n)
        #pragma unroll
        for (int r2 = 0; r2 < 4; ++r2) {
          v4f v = *(const v4f*)(xb + ((n * 4 + r2) << 10) + 16 * lane);
          acc[mm][n][4 * r2]     += v[0];
          acc[mm][n][4 * r2 + 1] += v[1];
          acc[mm][n][4 * r2 + 2] += v[2];
          acc[mm][n][4 * r2 + 3] += v[3];
        }
    }
    __syncthreads();                   // WAR guard before next round's writes
  }

  // epilogue (wave0): plain cached stores (L2 merges into full lines).
  // D col=lane&31 -> F, row=(reg&3)+8*(reg>>2)+4*hi -> t
  if (wid == 0) {
    #pragma unroll
    for (int m = 0; m < 2; ++m)
      #pragma unroll
      for (int n = 0; n < 4; ++n) {
        const int F = 32 * n + row;
        const float sc = scale[F];
        float* op = out + (size_t)(bc * NF + F) * T_OUT + t0 + 32 * m + 4 * hi;
        #pragma unroll
        for (int r2 = 0; r2 < 4; ++r2) {
          v4f o = {acc[m][n][4 * r2] * sc, acc[m][n][4 * r2 + 1] * sc,
                   acc[m][n][4 * r2 + 2] * sc, acc[m][n][4 * r2 + 3] * sc};
          *(v4f*)(op + 8 * r2) = o;
        }
      }
  }
}

extern "C" void kernel_launch(void* const* d_in, const int* in_sizes, int n_in,
                              void* d_out, int out_size, void* d_ws, size_t ws_size,
                              hipStream_t stream) {
  const float* noise = (const float*)d_in[0];   // (2, 8, 9095) fp32
  const float* filt  = (const float*)d_in[1];   // (128, 5000) fp32
  const float* scale = (const float*)d_in[2];   // (1, 128, 1) fp32
  float* out = (float*)d_out;                   // (2, 1024, 4096) fp32

  unsigned short* swz  = (unsigned short*)d_ws;             // 1.44 MB
  unsigned short* xb16 = (unsigned short*)((char*)d_ws + SWZ_BYTES); // 1.20 MB

  const int x_blocks = (4 * CS + 255) / 256;                // 2336
  build_pre<<<352 + x_blocks, 256, 0, stream>>>(filt, noise, swz, xb16);
  blur_mfma<<<1024, 128, 0, stream>>>(xb16, swz, scale, out);
}

// Round 12
// 119.555 us; speedup vs baseline: 1.1492x; 1.1492x over previous
//
#include <hip/hip_runtime.h>
#include <hip/hip_bf16.h>

// BlurredNoise via MFMA implicit GEMM, round 20 = x-image-in-LDS + 4-wave
// 128t blocks.
// R19 proved A must not ride the VMEM pipe (A+B share one FIFO -> 75us).
// R16/R18 budget showed the LDS path as-built costs ~50k cyc/CU, much of it
// stage-writes + bank conflicts + per-window vmcnt(0) drains (stage x-loads
// are newest in the vmcnt FIFO -> waiting drains all D B-prefetches, every
// window; why T14 never helped). Fix both:
// (1) whole-k x image in LDS, loaded ONCE in the prologue from R19's
//     verified global 4-shifted-copy bf16 image (copy p = row&3 makes every
//     A-frag two 8B-aligned ds_read_b64). Copy stride 12320B (3080 words
//     == 8 mod 32) -> conflict-free reads. All mid-loop staging deleted;
//     lgkmcnt = pure A stream, vmcnt = pure B stream (counted, never 0).
// (2) 4-wave blocks over 128t (2 t-halves x 2-way k-split): x image shared,
//     B-VMEM per CU HALVED (2 blocks/CU x 528KB), still 8 waves/CU.
//     1-round LDS reduction per t-half pair (reuses dead x region).
// Uniform UB=12 rolled bodies, runtime iters, compile-time reg indices.
// k-cut (cost-balanced): k0 = W4 s0..23 + W3 s24..59 + W2 s60..107;
//                        k1 = W2 s108..131 + W1 s132..323.
// out[bc][F][t] = scale[F] * sum_j x[bc][t+j] * k[F][j]

#define KS      5000
#define IN_SEQ  9095
#define T_OUT   4096
#define NBC     16
#define NF      128
#define SWZSTEP 352               // B rows per tile (s>=313 all-zero via clamp)
#define FRONT   192               // x front zero pad (elements)
#define XPS2    9344              // bf16 copy row stride (elements)
#define CS      (NBC*XPS2)        // elems per global copy = 149,504
#define SWZ_BYTES (4*SWZSTEP*1024)    // 1,441,792
#define LSTRIDE 12320             // bytes per LDS x copy; /4=3080 == 8 mod 32
#define ACONST  10592             // 2*(KS-16+FRONT+120)

typedef __attribute__((ext_vector_type(8)))  short v8s;
typedef __attribute__((ext_vector_type(4)))  float v4f;
typedef __attribute__((ext_vector_type(16))) float v16f;

__device__ __forceinline__ unsigned short f2b(float v) {
  union { __hip_bfloat16 h; unsigned short u; } cv;
  cv.h = __float2bfloat16(v);   // RNE
  return cv.u;
}

// ---- fused pre-kernel: (a) filters -> 32x32x16 B-frags; (b) 4 shifted bf16
// x copies in GLOBAL: xb16[p][bc][i] = x_bc[i - FRONT + p], zeros outside ----
__global__ void build_pre(const float* __restrict__ filt,
                          const float* __restrict__ noise,
                          unsigned short* __restrict__ swz,
                          unsigned short* __restrict__ xb16) {
  const int b = blockIdx.x;
  if (b < 352) {                       // swz job: 4 tiles x 352 rows, 64 lanes/frag
    const int i = b * 256 + threadIdx.x;
    if (i >= 4 * SWZSTEP * 64) return;
    const int lane = i & 63;
    const int frag = i >> 6;
    const int ft = frag / SWZSTEP;
    const int s  = frag - ft * SWZSTEP;
    const int col = lane & 31;          // filter within tile
    const int hi  = lane >> 5;          // k-group (8 taps)
    const int jg0 = KS - 16 * (s + 1) + 8 * hi;
    const float* row = filt + (size_t)(ft * 32 + col) * KS;
    unsigned short o[8];
    #pragma unroll
    for (int j = 0; j < 8; ++j) {
      int jg = jg0 + j;
      int jc = jg < 0 ? 0 : jg;          // clamp ADDRESS, select VALUE
      float v = (jg >= 0 && jg < KS) ? row[jc] : 0.0f;
      o[j] = f2b(v);
    }
    *(uint4*)(swz + (((size_t)(ft * SWZSTEP + s)) << 9) + (lane << 3)) = *(uint4*)o;
  } else {                             // xb16 job: 4 copies x 16 rows x XPS2
    const int i = (b - 352) * 256 + threadIdx.x;
    if (i >= 4 * CS) return;
    const int p   = i / CS;
    const int rem = i - p * CS;
    const int r   = rem / XPS2;
    const int col = rem - r * XPS2;
    const int lg  = col - FRONT + p;
    const float v = (lg >= 0 && lg < IN_SEQ) ? noise[r * IN_SEQ + lg] : 0.0f;
    xb16[i] = f2b(v);
  }
}

// ---- one rolled region of the k-loop ----
// W: live 32-F tiles (tiles 4-W..3); D: B-prefetch depth (divides 12);
// sb0/iters RUNTIME. Per step: A ring prefetch dist 3 (2 m-streams, 2x
// ds_read_b64 each from the LDS x image), 2W MFMA, W B-refill dwordx4.
// All register indices compile-time (rule 20). No staging in the loop.
template<int W, int D>
__device__ __forceinline__ void run_roll(
    const char* __restrict__ swzg, const char* abase, int lane,
    int sb0, int iters, v16f (&acc)[2][4])
{
  v8s breg[D][W];
  v8s areg[4][2];                      // [ring slot][m-stream]

  const char* sp[W];
  #pragma unroll
  for (int w = 0; w < W; ++w)
    sp[w] = swzg + (((size_t)((4 - W + w) * SWZSTEP + sb0)) << 10) + 16 * lane;

  const char* ap = abase - 32 * sb0;   // LDS A byte ptr at region step 0

  // prologue: B depth D; A ring slots 0..2 = steps sb0..sb0+2
  #pragma unroll
  for (int d = 0; d < D; ++d)
    #pragma unroll
    for (int w = 0; w < W; ++w)
      breg[d][w] = *(const v8s*)(sp[w] + (d << 10));
  #pragma unroll
  for (int j = 0; j < 3; ++j)
    #pragma unroll
    for (int m = 0; m < 2; ++m) {
      *(uint2*)&areg[j][m]       = *(const uint2*)(ap - 32 * j + 64 * m);
      *((uint2*)&areg[j][m] + 1) = *(const uint2*)(ap - 32 * j + 64 * m + 8);
    }

  #pragma unroll 1
  for (int g = 0; g < iters; ++g) {
    #pragma unroll
    for (int ii = 0; ii < 12; ++ii) {
      // A prefetch for step ii+3 (region-tail reads stay inside the padded
      // image; values beyond the region are never consumed)
      #pragma unroll
      for (int m = 0; m < 2; ++m) {
        *(uint2*)&areg[(ii + 3) & 3][m] =
            *(const uint2*)(ap - 32 * (ii + 3) + 64 * m);
        *((uint2*)&areg[(ii + 3) & 3][m] + 1) =
            *(const uint2*)(ap - 32 * (ii + 3) + 64 * m + 8);
      }
      // MFMA: one A fragment per m-stream x W live B tiles (B shared)
      #pragma unroll
      for (int w = 0; w < W; ++w)
        #pragma unroll
        for (int m = 0; m < 2; ++m)
          acc[m][4 - W + w] = __builtin_amdgcn_mfma_f32_32x32x16_bf16(
              areg[ii & 3][m], breg[ii % D][w], acc[m][4 - W + w], 0, 0, 0);
      // B refill: slot ii%D <- step ii+D (tail over-reads: rows < SWZSTEP, dead)
      #pragma unroll
      for (int w = 0; w < W; ++w)
        breg[ii % D][w] = *(const v8s*)(sp[w] + ((ii + D) << 10));
    }
    #pragma unroll
    for (int w = 0; w < W; ++w) sp[w] += (12 << 10);
    ap -= 32 * 12;
  }
}

// ---- main kernel: 512 blocks x 256 threads ----
// wave w: th = w&1 (t-half of the 128t tile), kk = w>>1 (k-split half).
__global__ __launch_bounds__(256, 2) void blur_mfma(
    const unsigned short* __restrict__ xb16,
    const unsigned short* __restrict__ swz,
    const float* __restrict__ scale,
    float* __restrict__ out)
{
  __shared__ __align__(16) char xb[4 * LSTRIDE];   // 49,280 B
  const int tid  = threadIdx.x;
  const int lane = tid & 63;
  const int wid  = tid >> 6;
  const int th   = wid & 1;
  const int kk   = wid >> 1;
  const int b  = blockIdx.x;
  const int bc = b >> 5;                 // 16 bc x 32 t-chunks of 128
  const int t0 = (b & 31) << 7;          // 128 output t per block
  const int row = lane & 31, hi = lane >> 5, p = row & 3;
  const char* swzg = (const char*)swz;

  // ---- prologue: copy wave wid's x copy (12 KB) global -> LDS, once ----
  {
    const char* gsrc = (const char*)xb16 +
        2 * ((ptrdiff_t)wid * CS + (ptrdiff_t)bc * XPS2 + (t0 - 120));
    const char* gend = (const char*)xb16 + 2 * (ptrdiff_t)(4 * CS) - 16;
    char* ldst = xb + wid * LSTRIDE;
    uint4 tmp[12];
    #pragma unroll
    for (int j = 0; j < 12; ++j) {
      const char* s = gsrc + j * 1024 + 16 * lane;
      s = (s > gend) ? gend : s;         // tail clamp (values dead, addr safe)
      tmp[j] = *(const uint4*)s;
    }
    #pragma unroll
    for (int j = 0; j < 12; ++j)
      *(uint4*)(ldst + j * 1024 + 16 * lane) = tmp[j];
  }
  __syncthreads();

  // A base: copy p, byte = p*LSTRIDE + ACONST + 2(row-p) + 16hi + 128th
  // (+64 per m-stream, -32 per step; 8B-aligned since (row-p)%4==0)
  const char* abase = xb + p * LSTRIDE + ACONST + 2 * (row - p)
                         + 16 * hi + 128 * th;

  v16f acc[2][4];
  #pragma unroll
  for (int m = 0; m < 2; ++m)
    #pragma unroll
    for (int n = 0; n < 4; ++n)
      #pragma unroll
      for (int j = 0; j < 16; ++j) acc[m][n][j] = 0.0f;

  // regions (live: W4 s<20, W3 <49, W2 <124, W1 <313; extras hit zero B rows)
  if (kk == 0) {
    run_roll<4,  3>(swzg, abase, lane,   0, 2, acc);   // s0..23
    run_roll<3,  4>(swzg, abase, lane,  24, 3, acc);   // s24..59
    run_roll<2,  6>(swzg, abase, lane,  60, 4, acc);   // s60..107
  } else {
    run_roll<2,  6>(swzg, abase, lane, 108, 2, acc);   // s108..131
    run_roll<1, 12>(swzg, abase, lane, 132, 16, acc);  // s132..323
  }

  // cross-wave reduction (per t-half pair): k1 waves write, k0 waves add.
  // Reuses the (now dead) x image LDS; th picks a disjoint 16KB region.
  __syncthreads();
  #pragma unroll
  for (int mm = 0; mm < 2; ++mm) {
    if (kk == 1) {
      #pragma unroll
      for (int n = 0; n < 4; ++n)
        #pragma unroll
        for (int r2 = 0; r2 < 4; ++r2) {
          v4f v = {acc[mm][n][4 * r2],     acc[mm][n][4 * r2 + 1],
                   acc[mm][n][4 * r2 + 2], acc[mm][n][4 * r2 + 3]};
          *(v4f*)(xb + th * 16384 + ((n * 4 + r2) << 10) + 16 * lane) = v;
        }
    }
    __syncthreads();
    if (kk == 0) {
      #pragma unroll
      for (int n = 0; n < 4; ++n)
        #pragma unroll
        for (int r2 = 0; r2 < 4; ++r2) {
          v4f v = *(const v4f*)(xb + th * 16384 + ((n * 4 + r2) << 10) + 16 * lane);
          acc[mm][n][4 * r2]     += v[0];
          acc[mm][n][4 * r2 + 1] += v[1];
          acc[mm][n][4 * r2 + 2] += v[2];
          acc[mm][n][4 * r2 + 3] += v[3];
        }
    }
    __syncthreads();                   // WAR guard before next round's writes
  }

  // epilogue (k0 waves, one per t-half): plain cached stores.
  // D col=lane&31 -> F, row=(reg&3)+8*(reg>>2)+4*hi -> t
  if (kk == 0) {
    #pragma unroll
    for (int m = 0; m < 2; ++m)
      #pragma unroll
      for (int n = 0; n < 4; ++n) {
        const int F = 32 * n + row;
        const float sc = scale[F];
        float* op = out + (size_t)(bc * NF + F) * T_OUT
                        + t0 + 64 * th + 32 * m + 4 * hi;
        #pragma unroll
        for (int r2 = 0; r2 < 4; ++r2) {
          v4f o = {acc[m][n][4 * r2] * sc, acc[m][n][4 * r2 + 1] * sc,
                   acc[m][n][4 * r2 + 2] * sc, acc[m][n][4 * r2 + 3] * sc};
          *(v4f*)(op + 8 * r2) = o;
        }
      }
  }
}

extern "C" void kernel_launch(void* const* d_in, const int* in_sizes, int n_in,
                              void* d_out, int out_size, void* d_ws, size_t ws_size,
                              hipStream_t stream) {
  const float* noise = (const float*)d_in[0];   // (2, 8, 9095) fp32
  const float* filt  = (const float*)d_in[1];   // (128, 5000) fp32
  const float* scale = (const float*)d_in[2];   // (1, 128, 1) fp32
  float* out = (float*)d_out;                   // (2, 1024, 4096) fp32

  unsigned short* swz  = (unsigned short*)d_ws;                      // 1.44 MB
  unsigned short* xb16 = (unsigned short*)((char*)d_ws + SWZ_BYTES); // 1.20 MB

  const int x_blocks = (4 * CS + 255) / 256;                // 2336
  build_pre<<<352 + x_blocks, 256, 0, stream>>>(filt, noise, swz, xb16);
  blur_mfma<<<512, 256, 0, stream>>>(xb16, swz, scale, out);
}